// Round 6
// baseline (257.181 us; speedup 1.0000x reference)
//
#include <hip/hip_runtime.h>
#include <hip/hip_fp16.h>

// MDLSTM 64x64 grid, B=32, I=64, O=128.
//   K1 lut:   lut[p] = cell index (i*64+j) for diagonal-packed order p
//   K2 prep:  wt[g][o][k] (f16) = -W_g[k][o] * log2(e)
//   K3 gemm:  pair-interleaved preactivations, z~ = -(x@W+b)*log2e:
//               plane01[w][p] : dword = (f0,f1) f16 pair
//               plane23[w][p] : dword = (i,o)  f16 pair
//               plane4 [w][p] : f16   = c
//   K4 recur: DUAL-PACKED: one wave handles problems A=(b',o) and B=(b'+16,o),
//             B time-shifted 64 steps (complementary triangular wavefronts).
//             Lane j: A while iv=d-j in [0,64), B while iv in [64,128).
//             Left-neighbor via DPP wave_shr1; merged-rcp gates (10 trans/step).
//             s stored f16 into dead plane4 slots of the owning problem.
//   K5 transpose: plane4 [w][p] f16 -> out [cell][w] f32.
// Workspace: planes 64+64+32 = 160 MiB | lut 16 KiB | wt 80 KiB.

#define P23_OFF  ((size_t)64 << 20)
#define P4_OFF   ((size_t)128 << 20)
#define GX_BYTES ((size_t)160 << 20)
#define LOG2E    1.4426950408889634f

typedef __attribute__((ext_vector_type(8))) _Float16 half8;
typedef __attribute__((ext_vector_type(2))) __fp16 fp16x2;
typedef __attribute__((ext_vector_type(4))) float f32x4;

__device__ __forceinline__ unsigned pkrtz(float a, float b) {
    union { fp16x2 h; unsigned u; } c;
    c.h = __builtin_amdgcn_cvt_pkrtz(a, b);
    return c.u;
}
// whole-wave shift right by 1 lane; lane 0 gets 0 (bound_ctrl)
__device__ __forceinline__ float wave_shr1(float v) {
    return __int_as_float(
        __builtin_amdgcn_update_dpp(0, __float_as_int(v), 0x138, 0xf, 0xf, true));
}

__device__ __forceinline__ int diag_off(int d) {
    return (d < 64) ? ((d * (d + 1)) >> 1) : (4096 - (((127 - d) * (128 - d)) >> 1));
}

__global__ __launch_bounds__(256) void lut_kernel(int* __restrict__ lut) {
    int t = blockIdx.x * 256 + threadIdx.x;   // 0..4095 = i*64+j
    int i = t >> 6, j = t & 63;
    int d = i + j;
    int jmin = (d > 63) ? (d - 63) : 0;
    lut[diag_off(d) + j - jmin] = t;
}

// wt[g][o][k] = -(W_g[k][o]) * log2e  as f16
__global__ __launch_bounds__(256) void prep_w(
    const float* __restrict__ wf, const float* __restrict__ wi,
    const float* __restrict__ wo, const float* __restrict__ wc,
    _Float16* __restrict__ wt)
{
    const int g = blockIdx.x;
    const float* W = (g == 0) ? wf : (g == 1) ? (wf + 8192)
                   : (g == 2) ? wi : (g == 3) ? wo : wc;
    const int t = threadIdx.x;
    const int o = t >> 1, k0 = (t & 1) * 32;
    _Float16 buf[32];
#pragma unroll
    for (int k = 0; k < 32; ++k)
        buf[k] = (_Float16)(-W[(k0 + k) * 128 + o] * LOG2E);
    _Float16* dst = wt + ((size_t)g * 128 + o) * 64 + k0;
#pragma unroll
    for (int q = 0; q < 4; ++q) *(half8*)(dst + q * 8) = *(half8*)(buf + q * 8);
}

// MFMA GEMM: tile 128p x 128o, K=64. grid (32 p-tiles, 32 b).
__global__ __launch_bounds__(256, 2) void gemm_kernel(
    const float* __restrict__ x, const _Float16* __restrict__ wt,
    const float* __restrict__ biasf, const float* __restrict__ biasi,
    const float* __restrict__ biaso, const float* __restrict__ biasc,
    const int* __restrict__ lut, char* __restrict__ gx)
{
    __shared__ _Float16 As[128][72];     // [p][k]
    const int t  = threadIdx.x;
    const int p0 = blockIdx.x * 128;
    const int b  = blockIdx.y;

    // stage A: x rows (via lut) -> f16, As[p][k]
    {
        int r = t >> 1, k0 = (t & 1) * 32;
        int cell = lut[p0 + r];
        const float* xr = x + ((size_t)cell * 32 + b) * 64 + k0;
#pragma unroll
        for (int it = 0; it < 4; ++it) {
            float4 v0 = *(const float4*)(xr + it * 8);
            float4 v1 = *(const float4*)(xr + it * 8 + 4);
            half8 h;
            h[0] = (_Float16)v0.x; h[1] = (_Float16)v0.y;
            h[2] = (_Float16)v0.z; h[3] = (_Float16)v0.w;
            h[4] = (_Float16)v1.x; h[5] = (_Float16)v1.y;
            h[6] = (_Float16)v1.z; h[7] = (_Float16)v1.w;
            *(half8*)&As[r][k0 + it * 8] = h;
        }
    }
    __syncthreads();

    const int lane = t & 63;
    const int wv   = __builtin_amdgcn_readfirstlane(t >> 6);
    const int m    = lane & 15;
    const int quad = lane >> 4;
    const int o0   = wv * 32 + m;       // of=0 column
    const int o1   = o0 + 16;           // of=1 column
    const size_t row0 = (size_t)(b * 128 + o0) * 4096;
    const size_t row1 = (size_t)(b * 128 + o1) * 4096;
    const int pq = p0 + quad * 4;

    // A-fragments loaded ONCE, reused across all 3 phases
    half8 A0r[8], A1r[8];
#pragma unroll
    for (int pf = 0; pf < 8; ++pf) {
        A0r[pf] = *(const half8*)&As[pf * 16 + m][quad * 8];
        A1r[pf] = *(const half8*)&As[pf * 16 + m][32 + quad * 8];
    }

    // -------- pair phase: gates (ga, gb) -> packed dword plane --------
    auto pair_phase = [&](const _Float16* wga, const _Float16* wgb,
                          const float* bA, const float* bB, char* plane) {
        half8 ba0[2], ba1[2], bb0[2], bb1[2];
#pragma unroll
        for (int kh = 0; kh < 2; ++kh) {
            ba0[kh] = *(const half8*)(wga + o0 * 64 + kh * 32 + quad * 8);
            ba1[kh] = *(const half8*)(wga + o1 * 64 + kh * 32 + quad * 8);
            bb0[kh] = *(const half8*)(wgb + o0 * 64 + kh * 32 + quad * 8);
            bb1[kh] = *(const half8*)(wgb + o1 * 64 + kh * 32 + quad * 8);
        }
        f32x4 aA[8][2] = {}, aB[8][2] = {};
#pragma unroll
        for (int pf = 0; pf < 8; ++pf) {
            aA[pf][0] = __builtin_amdgcn_mfma_f32_16x16x32_f16(A0r[pf], ba0[0], aA[pf][0], 0, 0, 0);
            aA[pf][0] = __builtin_amdgcn_mfma_f32_16x16x32_f16(A1r[pf], ba0[1], aA[pf][0], 0, 0, 0);
            aA[pf][1] = __builtin_amdgcn_mfma_f32_16x16x32_f16(A0r[pf], ba1[0], aA[pf][1], 0, 0, 0);
            aA[pf][1] = __builtin_amdgcn_mfma_f32_16x16x32_f16(A1r[pf], ba1[1], aA[pf][1], 0, 0, 0);
            aB[pf][0] = __builtin_amdgcn_mfma_f32_16x16x32_f16(A0r[pf], bb0[0], aB[pf][0], 0, 0, 0);
            aB[pf][0] = __builtin_amdgcn_mfma_f32_16x16x32_f16(A1r[pf], bb0[1], aB[pf][0], 0, 0, 0);
            aB[pf][1] = __builtin_amdgcn_mfma_f32_16x16x32_f16(A0r[pf], bb1[0], aB[pf][1], 0, 0, 0);
            aB[pf][1] = __builtin_amdgcn_mfma_f32_16x16x32_f16(A1r[pf], bb1[1], aB[pf][1], 0, 0, 0);
        }
        float sA0 = -bA[o0] * LOG2E, sA1 = -bA[o1] * LOG2E;
        float sB0 = -bB[o0] * LOG2E, sB1 = -bB[o1] * LOG2E;
#pragma unroll
        for (int pf = 0; pf < 8; ++pf) {
#pragma unroll
            for (int of = 0; of < 2; ++of) {
                float sa = of ? sA1 : sA0, sb = of ? sB1 : sB0;
                f32x4 va = aA[pf][of], vb = aB[pf][of];
                uint4 st;
                st.x = pkrtz(va[0] + sa, vb[0] + sb);
                st.y = pkrtz(va[1] + sa, vb[1] + sb);
                st.z = pkrtz(va[2] + sa, vb[2] + sb);
                st.w = pkrtz(va[3] + sa, vb[3] + sb);
                size_t row = of ? row1 : row0;
                *(uint4*)(plane + (row + pq + pf * 16) * 4) = st;
            }
        }
    };
    pair_phase(wt,            wt + 8192,     biasf, biasf + 128, gx);
    pair_phase(wt + 2 * 8192, wt + 3 * 8192, biasi, biaso,       gx + P23_OFF);

    // -------- single phase: gate c -> f16 plane4 --------
    {
        const _Float16* wg = wt + 4 * 8192;
        half8 b0[2], b1[2];
#pragma unroll
        for (int kh = 0; kh < 2; ++kh) {
            b0[kh] = *(const half8*)(wg + o0 * 64 + kh * 32 + quad * 8);
            b1[kh] = *(const half8*)(wg + o1 * 64 + kh * 32 + quad * 8);
        }
        f32x4 ac[8][2] = {};
#pragma unroll
        for (int pf = 0; pf < 8; ++pf) {
            ac[pf][0] = __builtin_amdgcn_mfma_f32_16x16x32_f16(A0r[pf], b0[0], ac[pf][0], 0, 0, 0);
            ac[pf][0] = __builtin_amdgcn_mfma_f32_16x16x32_f16(A1r[pf], b0[1], ac[pf][0], 0, 0, 0);
            ac[pf][1] = __builtin_amdgcn_mfma_f32_16x16x32_f16(A0r[pf], b1[0], ac[pf][1], 0, 0, 0);
            ac[pf][1] = __builtin_amdgcn_mfma_f32_16x16x32_f16(A1r[pf], b1[1], ac[pf][1], 0, 0, 0);
        }
        float s0 = -biasc[o0] * LOG2E, s1 = -biasc[o1] * LOG2E;
        char* plane = gx + P4_OFF;
#pragma unroll
        for (int pf = 0; pf < 8; ++pf) {
#pragma unroll
            for (int of = 0; of < 2; ++of) {
                float sb = of ? s1 : s0;
                f32x4 v = ac[pf][of];
                uint2 st;
                st.x = pkrtz(v[0] + sb, v[1] + sb);
                st.y = pkrtz(v[2] + sb, v[3] + sb);
                size_t row = of ? row1 : row0;
                *(uint2*)(plane + (row + pq + pf * 16) * 2) = st;
            }
        }
    }
}

// DUAL-PACKED recurrence: 2048 waves; wave w'=(b',o) handles A=(b',o) and
// B=(b'+16,o). Lane j = column j. iv = d-j: A rows iv in [0,64), B rows iv-64.
// Row A-index in gx = w', B-index = w'+2048 (byte deltas 1<<25 / 1<<24).
__global__ __launch_bounds__(256) void recur_kernel(
    char* __restrict__ gx,
    const float* __restrict__ uf, const float* __restrict__ ui,
    const float* __restrict__ uo, const float* __restrict__ uc)
{
    const int lane = threadIdx.x & 63;
    const int w = __builtin_amdgcn_readfirstlane(blockIdx.x * 4 + (threadIdx.x >> 6)); // 0..2047
    const int o = w & 127;

    const float nf00 = -uf[o] * LOG2E,       nf01 = -uf[128 + o] * LOG2E;
    const float nf10 = -uf[256 + o] * LOG2E, nf11 = -uf[384 + o] * LOG2E;
    const float ni0 = -ui[o] * LOG2E, ni1 = -ui[128 + o] * LOG2E;
    const float no0 = -uo[o] * LOG2E, no1 = -uo[128 + o] * LOG2E;
    const float nc0 = -uc[o] * LOG2E, nc1 = -uc[128 + o] * LOG2E;

    const char* b01 = gx + (size_t)w * 16384;
    const char* b23 = gx + P23_OFF + (size_t)w * 16384;
    const char* b4  = gx + P4_OFF + (size_t)w * 8192;
    char*       s4  = gx + P4_OFF + (size_t)w * 8192;
    const int l4 = lane * 4, l2 = lane * 2;

    // uniform byte offsets within a row: QA* prefetch for A, QB* for B
    // (QB pre-folded with the +2048-row region delta).
    int QA01 = 0, QA4 = 0;
    int QB01 = 1 << 25, QB4 = 1 << 24;
    int TA4 = 0, TB4 = 1 << 24;           // store offsets

    int iv = -lane;                        // current row index d - j
    float c0,c1,c2,c3,c4, n0,n1,n2,n3,n4;

#define LDSEL(v0_,v1_,v2_,v3_,v4_, PF) { \
    bool inApf_ = (unsigned)(iv + (PF)) < 64u; \
    int s01_ = (inApf_ ? QA01 : QB01) + l4; \
    int s4_  = (inApf_ ? QA4  : QB4)  + l2; \
    __half2 h01 = *(const __half2*)(b01 + s01_); \
    __half2 h23 = *(const __half2*)(b23 + s01_); \
    _Float16 h4 = *(const _Float16*)(b4 + s4_); \
    v0_ = __low2float(h01); v1_ = __high2float(h01); \
    v2_ = __low2float(h23); v3_ = __high2float(h23); \
    v4_ = (float)h4; }

    // prologue: load diag 0 (consumed step 0) and diag 1 (consumed step 1)
    LDSEL(c0,c1,c2,c3,c4, 0);  QA01 += 1 * 4;  QA4 += 1 * 2;   // advA(0)=1
    LDSEL(n0,n1,n2,n3,n4, 1);  QA01 += 2 * 4;  QA4 += 2 * 2;   // advA(1)=2

    float s_prev = 0.f, h_prev = 0.f;

#pragma unroll 2
    for (int d = 0; d < 191; ++d) {
        // prefetch diag d+2 (per-lane A/B select based on iv+2)
        float t0,t1,t2,t3,t4;
        LDSEL(t0,t1,t2,t3,t4, 2);
        {   // uniform offset advances (A clamps after diag 126, B before 0/after)
            int adA = min(d + 3, 124 - d); adA = max(adA, 0);
            int adB = min(d - 61, 188 - d); adB = max(adB, 0);
            QA01 += adA * 4; QA4 += adA * 2;
            QB01 += adB * 4; QB4 += adB * 2;
        }

        // left-neighbor via whole-wave DPP shift (lane 0 -> 0)
        float sl = wave_shr1(s_prev);
        float hl = wave_shr1(h_prev);
        // own up-neighbor: zero at row starts (iv % 64 == 0) AFTER neighbor read
        bool rs = (iv & 63) == 0;
        float su = rs ? 0.f : s_prev;
        float hu = rs ? 0.f : h_prev;

        float zf0 = fmaf(hu, nf00, fmaf(hl, nf01, c0));
        float zf1 = fmaf(hu, nf10, fmaf(hl, nf11, c1));
        float zi  = fmaf(hu, ni0,  fmaf(hl, ni1,  c2));
        float zo  = fmaf(hu, no0,  fmaf(hl, no1,  c3));
        float zc  = fmaf(hu, nc0,  fmaf(hl, nc1,  c4));

        float E0 = __builtin_amdgcn_exp2f(zf0);
        float E1 = __builtin_amdgcn_exp2f(zf1);
        float Ei = __builtin_amdgcn_exp2f(zi);
        float Eo = __builtin_amdgcn_exp2f(zo);
        float Ec = __builtin_amdgcn_exp2f(zc);
        float A0 = 1.f + E0, A1 = 1.f + E1;
        // f0*su + f1*sl = (su*A1 + sl*A0) / (A0*A1)
        float F   = fmaf(su, A1, sl * A0) * __builtin_amdgcn_rcpf(A0 * A1);
        // ig*cg = 1 / ((1+Ei)(1+Ec))
        float icg = __builtin_amdgcn_rcpf(fmaf(Ei, Ec, (Ei + Ec) + 1.f));
        float og  = __builtin_amdgcn_rcpf(1.f + Eo);

        float s  = icg + F;
        float E2 = __builtin_amdgcn_exp2f((s + s) * LOG2E);
        float th = fmaf(-2.f, __builtin_amdgcn_rcpf(E2 + 1.f), 1.f);
        float h  = og * th;

        bool act = (unsigned)iv < 128u;
        bool inA = (unsigned)iv < 64u;
        int selS = (inA ? TA4 : TB4) + l2;
        if (act) *(_Float16*)(s4 + selS) = (_Float16)s;  // dead slot, coalesced
        {
            int aA = min(d + 1, 126 - d); aA = max(aA, 0);
            int aB = min(d - 63, 190 - d); aB = max(aB, 0);
            TA4 += aA * 2; TB4 += aB * 2;
        }

        s_prev = s; h_prev = h;
        iv += 1;
        c0 = n0; c1 = n1; c2 = n2; c3 = n3; c4 = n4;
        n0 = t0; n1 = t1; n2 = t2; n3 = t3; n4 = t4;
    }
#undef LDSEL
}

// plane4 [w][p] f16 -> out[cell][w] f32.  Tile: 64 p x 256 w.
__global__ __launch_bounds__(256) void transpose_kernel(
    const char* __restrict__ gx, const int* __restrict__ lut,
    float* __restrict__ out)
{
    __shared__ _Float16 T[256][80];
    const _Float16* p4 = (const _Float16*)(gx + P4_OFF);
    const int t  = threadIdx.x;
    const int p0 = blockIdx.x * 64;
    const int w0 = blockIdx.y * 256;
#pragma unroll
    for (int it = 0; it < 8; ++it) {
        int wl = it * 32 + (t >> 3), pl = (t & 7) * 8;
        *(half8*)&T[wl][pl] =
            *(const half8*)(p4 + (size_t)(w0 + wl) * 4096 + p0 + pl);
    }
    __syncthreads();
    float* ob = out + w0 + t;
#pragma unroll 4
    for (int p = 0; p < 64; ++p) {
        int cell = lut[p0 + p];                 // block-uniform -> scalar load
        ob[(size_t)cell * 4096] = (float)T[t][p];
    }
}

extern "C" void kernel_launch(void* const* d_in, const int* in_sizes, int n_in,
                              void* d_out, int out_size, void* d_ws, size_t ws_size,
                              hipStream_t stream) {
    const float* x     = (const float*)d_in[0];
    const float* wf    = (const float*)d_in[1];
    const float* uf    = (const float*)d_in[2];
    const float* biasf = (const float*)d_in[3];
    const float* wi    = (const float*)d_in[4];
    const float* ui    = (const float*)d_in[5];
    const float* biasi = (const float*)d_in[6];
    const float* wo    = (const float*)d_in[7];
    const float* uo    = (const float*)d_in[8];
    const float* biaso = (const float*)d_in[9];
    const float* wc    = (const float*)d_in[10];
    const float* uc    = (const float*)d_in[11];
    const float* biasc = (const float*)d_in[12];
    float* out = (float*)d_out;

    char*     gx  = (char*)d_ws;
    int*      lut = (int*)(gx + GX_BYTES);
    _Float16* wt  = (_Float16*)((char*)lut + 16384);

    lut_kernel<<<16, 256, 0, stream>>>(lut);
    prep_w<<<5, 256, 0, stream>>>(wf, wi, wo, wc, wt);
    gemm_kernel<<<dim3(32, 32), 256, 0, stream>>>(
        x, wt, biasf, biasi, biaso, biasc, lut, gx);
    recur_kernel<<<512, 256, 0, stream>>>(gx, uf, ui, uo, uc);
    transpose_kernel<<<dim3(64, 16), 256, 0, stream>>>(gx, lut, out);
}

// Round 7
// 250.846 us; speedup vs baseline: 1.0253x; 1.0253x over previous
//
#include <hip/hip_runtime.h>
#include <hip/hip_fp16.h>

// MDLSTM 64x64 grid, B=32, I=64, O=128.
//   K1 lut:   lut[p] = cell index (i*64+j) for diagonal-packed order p
//   K2 prep:  wt[g][o][k] (f16) = -W_g[k][o] * log2(e)
//   K3 gemm:  pair-interleaved preactivations, z~ = -(x@W+b)*log2e:
//               plane01[w][p] : dword = (f0,f1) f16 pair
//               plane23[w][p] : dword = (i,o)  f16 pair
//               plane4 [w][p] : f16   = c
//             A-stage: 16 lanes/row -> 4 full rows x 256 B per load instr.
//   K4 recur: one wave per w=(b,o), lane j = column j, 127 anti-diag steps.
//             DPP wave_shr1 left-neighbor; merged-rcp gates (10 trans/step);
//             3 loads/step via scalar-advanced pointers.
//             s stored f16 into dead plane4 slots (consumed 2 steps earlier).
//   K5 transpose: plane4 [w][p] f16 -> out [cell][w] f32.
// Workspace: planes 64+64+32 = 160 MiB | lut 16 KiB | wt 80 KiB.

#define P23_OFF  ((size_t)64 << 20)
#define P4_OFF   ((size_t)128 << 20)
#define GX_BYTES ((size_t)160 << 20)
#define LOG2E    1.4426950408889634f

typedef __attribute__((ext_vector_type(8))) _Float16 half8;
typedef __attribute__((ext_vector_type(4))) _Float16 half4;
typedef __attribute__((ext_vector_type(2))) __fp16 fp16x2;
typedef __attribute__((ext_vector_type(4))) float f32x4;

__device__ __forceinline__ unsigned pkrtz(float a, float b) {
    union { fp16x2 h; unsigned u; } c;
    c.h = __builtin_amdgcn_cvt_pkrtz(a, b);
    return c.u;
}
// whole-wave shift right by 1 lane; lane 0 gets 0 (bound_ctrl)
__device__ __forceinline__ float wave_shr1(float v) {
    return __int_as_float(
        __builtin_amdgcn_update_dpp(0, __float_as_int(v), 0x138, 0xf, 0xf, true));
}

__device__ __forceinline__ int diag_off(int d) {
    return (d < 64) ? ((d * (d + 1)) >> 1) : (4096 - (((127 - d) * (128 - d)) >> 1));
}

__global__ __launch_bounds__(256) void lut_kernel(int* __restrict__ lut) {
    int t = blockIdx.x * 256 + threadIdx.x;   // 0..4095 = i*64+j
    int i = t >> 6, j = t & 63;
    int d = i + j;
    int jmin = (d > 63) ? (d - 63) : 0;
    lut[diag_off(d) + j - jmin] = t;
}

// wt[g][o][k] = -(W_g[k][o]) * log2e  as f16
__global__ __launch_bounds__(256) void prep_w(
    const float* __restrict__ wf, const float* __restrict__ wi,
    const float* __restrict__ wo, const float* __restrict__ wc,
    _Float16* __restrict__ wt)
{
    const int g = blockIdx.x;
    const float* W = (g == 0) ? wf : (g == 1) ? (wf + 8192)
                   : (g == 2) ? wi : (g == 3) ? wo : wc;
    const int t = threadIdx.x;
    const int o = t >> 1, k0 = (t & 1) * 32;
    _Float16 buf[32];
#pragma unroll
    for (int k = 0; k < 32; ++k)
        buf[k] = (_Float16)(-W[(k0 + k) * 128 + o] * LOG2E);
    _Float16* dst = wt + ((size_t)g * 128 + o) * 64 + k0;
#pragma unroll
    for (int q = 0; q < 4; ++q) *(half8*)(dst + q * 8) = *(half8*)(buf + q * 8);
}

// MFMA GEMM: tile 128p x 128o, K=64. grid (32 p-tiles, 32 b).
__global__ __launch_bounds__(256, 2) void gemm_kernel(
    const float* __restrict__ x, const _Float16* __restrict__ wt,
    const float* __restrict__ biasf, const float* __restrict__ biasi,
    const float* __restrict__ biaso, const float* __restrict__ biasc,
    const int* __restrict__ lut, char* __restrict__ gx)
{
    __shared__ _Float16 As[128][72];     // [p][k]
    const int t  = threadIdx.x;
    const int p0 = blockIdx.x * 128;
    const int b  = blockIdx.y;

    // stage A: 16 lanes per row -> each float4 instr covers 4 rows x 256 B
    {
        int r0 = t >> 4;            // 0..15
        int c4 = (t & 15) * 4;      // float index within row
#pragma unroll
        for (int it = 0; it < 8; ++it) {
            int r = r0 + it * 16;
            int cell = lut[p0 + r];
            float4 v = *(const float4*)(x + ((size_t)cell * 32 + b) * 64 + c4);
            half4 h;
            h[0] = (_Float16)v.x; h[1] = (_Float16)v.y;
            h[2] = (_Float16)v.z; h[3] = (_Float16)v.w;
            *(half4*)&As[r][c4] = h;
        }
    }
    __syncthreads();

    const int lane = t & 63;
    const int wv   = __builtin_amdgcn_readfirstlane(t >> 6);
    const int m    = lane & 15;
    const int quad = lane >> 4;
    const int o0   = wv * 32 + m;       // of=0 column
    const int o1   = o0 + 16;           // of=1 column
    const size_t row0 = (size_t)(b * 128 + o0) * 4096;
    const size_t row1 = (size_t)(b * 128 + o1) * 4096;
    const int pq = p0 + quad * 4;

    // -------- pair phase: gates (ga, gb) -> packed dword plane --------
    auto pair_phase = [&](const _Float16* wga, const _Float16* wgb,
                          const float* bA, const float* bB, char* plane) {
        half8 ba0[2], ba1[2], bb0[2], bb1[2];
#pragma unroll
        for (int kh = 0; kh < 2; ++kh) {
            ba0[kh] = *(const half8*)(wga + o0 * 64 + kh * 32 + quad * 8);
            ba1[kh] = *(const half8*)(wga + o1 * 64 + kh * 32 + quad * 8);
            bb0[kh] = *(const half8*)(wgb + o0 * 64 + kh * 32 + quad * 8);
            bb1[kh] = *(const half8*)(wgb + o1 * 64 + kh * 32 + quad * 8);
        }
        f32x4 aA[8][2] = {}, aB[8][2] = {};
#pragma unroll
        for (int pf = 0; pf < 8; ++pf) {
            half8 af0 = *(const half8*)&As[pf * 16 + m][quad * 8];
            half8 af1 = *(const half8*)&As[pf * 16 + m][32 + quad * 8];
            aA[pf][0] = __builtin_amdgcn_mfma_f32_16x16x32_f16(af0, ba0[0], aA[pf][0], 0, 0, 0);
            aA[pf][0] = __builtin_amdgcn_mfma_f32_16x16x32_f16(af1, ba0[1], aA[pf][0], 0, 0, 0);
            aA[pf][1] = __builtin_amdgcn_mfma_f32_16x16x32_f16(af0, ba1[0], aA[pf][1], 0, 0, 0);
            aA[pf][1] = __builtin_amdgcn_mfma_f32_16x16x32_f16(af1, ba1[1], aA[pf][1], 0, 0, 0);
            aB[pf][0] = __builtin_amdgcn_mfma_f32_16x16x32_f16(af0, bb0[0], aB[pf][0], 0, 0, 0);
            aB[pf][0] = __builtin_amdgcn_mfma_f32_16x16x32_f16(af1, bb0[1], aB[pf][0], 0, 0, 0);
            aB[pf][1] = __builtin_amdgcn_mfma_f32_16x16x32_f16(af0, bb1[0], aB[pf][1], 0, 0, 0);
            aB[pf][1] = __builtin_amdgcn_mfma_f32_16x16x32_f16(af1, bb1[1], aB[pf][1], 0, 0, 0);
        }
        float sA0 = -bA[o0] * LOG2E, sA1 = -bA[o1] * LOG2E;
        float sB0 = -bB[o0] * LOG2E, sB1 = -bB[o1] * LOG2E;
#pragma unroll
        for (int pf = 0; pf < 8; ++pf) {
#pragma unroll
            for (int of = 0; of < 2; ++of) {
                float sa = of ? sA1 : sA0, sb = of ? sB1 : sB0;
                f32x4 va = aA[pf][of], vb = aB[pf][of];
                uint4 st;
                st.x = pkrtz(va[0] + sa, vb[0] + sb);
                st.y = pkrtz(va[1] + sa, vb[1] + sb);
                st.z = pkrtz(va[2] + sa, vb[2] + sb);
                st.w = pkrtz(va[3] + sa, vb[3] + sb);
                size_t row = of ? row1 : row0;
                *(uint4*)(plane + (row + pq + pf * 16) * 4) = st;
            }
        }
    };
    pair_phase(wt,            wt + 8192,     biasf, biasf + 128, gx);
    pair_phase(wt + 2 * 8192, wt + 3 * 8192, biasi, biaso,       gx + P23_OFF);

    // -------- single phase: gate c -> f16 plane4 --------
    {
        const _Float16* wg = wt + 4 * 8192;
        half8 b0[2], b1[2];
#pragma unroll
        for (int kh = 0; kh < 2; ++kh) {
            b0[kh] = *(const half8*)(wg + o0 * 64 + kh * 32 + quad * 8);
            b1[kh] = *(const half8*)(wg + o1 * 64 + kh * 32 + quad * 8);
        }
        f32x4 ac[8][2] = {};
#pragma unroll
        for (int pf = 0; pf < 8; ++pf) {
            half8 af0 = *(const half8*)&As[pf * 16 + m][quad * 8];
            half8 af1 = *(const half8*)&As[pf * 16 + m][32 + quad * 8];
            ac[pf][0] = __builtin_amdgcn_mfma_f32_16x16x32_f16(af0, b0[0], ac[pf][0], 0, 0, 0);
            ac[pf][0] = __builtin_amdgcn_mfma_f32_16x16x32_f16(af1, b0[1], ac[pf][0], 0, 0, 0);
            ac[pf][1] = __builtin_amdgcn_mfma_f32_16x16x32_f16(af0, b1[0], ac[pf][1], 0, 0, 0);
            ac[pf][1] = __builtin_amdgcn_mfma_f32_16x16x32_f16(af1, b1[1], ac[pf][1], 0, 0, 0);
        }
        float s0 = -biasc[o0] * LOG2E, s1 = -biasc[o1] * LOG2E;
        char* plane = gx + P4_OFF;
#pragma unroll
        for (int pf = 0; pf < 8; ++pf) {
#pragma unroll
            for (int of = 0; of < 2; ++of) {
                float sb = of ? s1 : s0;
                f32x4 v = ac[pf][of];
                uint2 st;
                st.x = pkrtz(v[0] + sb, v[1] + sb);
                st.y = pkrtz(v[2] + sb, v[3] + sb);
                size_t row = of ? row1 : row0;
                *(uint2*)(plane + (row + pq + pf * 16) * 2) = st;
            }
        }
    }
}

// recurrence: wave w = (b,o); lane j = column j; 127 anti-diagonal steps.
// planes hold z~ = -(xW+b)*log2e; u pre-scaled -> sigmoid = rcp(1+exp2(z~)).
// Merged gates: F = (su*A1 + sl*A0)/(A0*A1), icg = 1/((1+Ei)(1+Ec)).
__global__ __launch_bounds__(256) void recur_kernel(
    char* __restrict__ gx,
    const float* __restrict__ uf, const float* __restrict__ ui,
    const float* __restrict__ uo, const float* __restrict__ uc)
{
    const int lane = threadIdx.x & 63;
    const int w = __builtin_amdgcn_readfirstlane(blockIdx.x * 4 + (threadIdx.x >> 6));
    const int o = w & 127;

    const float nf00 = -uf[o] * LOG2E,       nf01 = -uf[128 + o] * LOG2E;
    const float nf10 = -uf[256 + o] * LOG2E, nf11 = -uf[384 + o] * LOG2E;
    const float ni0 = -ui[o] * LOG2E, ni1 = -ui[128 + o] * LOG2E;
    const float no0 = -uo[o] * LOG2E, no1 = -uo[128 + o] * LOG2E;
    const float nc0 = -uc[o] * LOG2E, nc1 = -uc[128 + o] * LOG2E;

    // scalar-advanced base pointers (saddr codegen), fixed per-lane offsets
    const char* pc01 = gx + (size_t)w * 16384;
    const char* pc23 = gx + P23_OFF + (size_t)w * 16384;
    const char* pc4  = gx + P4_OFF + (size_t)w * 8192;
    char*       ps4  = gx + P4_OFF + (size_t)w * 8192;
    const int l4 = lane * 4, l2 = lane * 2;

    float c0,c1,c2,c3,c4, n0,n1,n2,n3,n4;

#define LD3(v0_,v1_,v2_,v3_,v4_) { \
    __half2 h01 = *(const __half2*)(pc01 + l4); \
    __half2 h23 = *(const __half2*)(pc23 + l4); \
    _Float16 h4 = *(const _Float16*)(pc4 + l2); \
    v0_ = __low2float(h01); v1_ = __high2float(h01); \
    v2_ = __low2float(h23); v3_ = __high2float(h23); \
    v4_ = (float)h4; }

    LD3(c0,c1,c2,c3,c4); pc01 += 4;  pc23 += 4;  pc4 += 2;   // -> diag 1
    LD3(n0,n1,n2,n3,n4); pc01 += 8;  pc23 += 8;  pc4 += 4;   // -> diag 2

    float s_prev = 0.f, h_prev = 0.f;

    for (int d = 0; d < 127; ++d) {
        float t0,t1,t2,t3,t4;
        LD3(t0,t1,t2,t3,t4);                    // prefetch diag d+2
        int del = min(d + 3, 124 - d); del = max(del, 0);
        pc01 += del * 4; pc23 += del * 4; pc4 += del * 2;

        // left-neighbor via whole-wave DPP shift (lane 0 -> 0)
        float sl = wave_shr1(s_prev);
        float hl = wave_shr1(h_prev);

        float zf0 = fmaf(h_prev, nf00, fmaf(hl, nf01, c0));
        float zf1 = fmaf(h_prev, nf10, fmaf(hl, nf11, c1));
        float zi  = fmaf(h_prev, ni0,  fmaf(hl, ni1,  c2));
        float zo  = fmaf(h_prev, no0,  fmaf(hl, no1,  c3));
        float zc  = fmaf(h_prev, nc0,  fmaf(hl, nc1,  c4));

        float E0 = __builtin_amdgcn_exp2f(zf0);
        float E1 = __builtin_amdgcn_exp2f(zf1);
        float Ei = __builtin_amdgcn_exp2f(zi);
        float Eo = __builtin_amdgcn_exp2f(zo);
        float Ec = __builtin_amdgcn_exp2f(zc);
        float A0 = 1.f + E0, A1 = 1.f + E1;
        // f0*s_up + f1*s_left = (su*A1 + sl*A0) / (A0*A1)
        float F   = fmaf(s_prev, A1, sl * A0) * __builtin_amdgcn_rcpf(A0 * A1);
        // ig*cg = 1 / ((1+Ei)(1+Ec))
        float icg = __builtin_amdgcn_rcpf(fmaf(Ei, Ec, (Ei + Ec) + 1.f));
        float og  = __builtin_amdgcn_rcpf(1.f + Eo);

        float s  = icg + F;
        float E2 = __builtin_amdgcn_exp2f((s + s) * LOG2E);
        float th = fmaf(-2.f, __builtin_amdgcn_rcpf(E2 + 1.f), 1.f);
        float h  = og * th;

        bool act = (unsigned)(d - lane) < 64u;   // i = d-j in [0,64)
        if (act) *(_Float16*)(ps4 + l2) = (_Float16)s;   // dead slot, coalesced
        ps4 += min(d + 1, 126 - d) * 2;

        s_prev = act ? s : 0.f;
        h_prev = act ? h : 0.f;
        c0 = n0; c1 = n1; c2 = n2; c3 = n3; c4 = n4;
        n0 = t0; n1 = t1; n2 = t2; n3 = t3; n4 = t4;
    }
#undef LD3
}

// plane4 [w][p] f16 -> out[cell][w] f32.  Tile: 64 p x 256 w.
__global__ __launch_bounds__(256) void transpose_kernel(
    const char* __restrict__ gx, const int* __restrict__ lut,
    float* __restrict__ out)
{
    __shared__ _Float16 T[256][80];
    const _Float16* p4 = (const _Float16*)(gx + P4_OFF);
    const int t  = threadIdx.x;
    const int p0 = blockIdx.x * 64;
    const int w0 = blockIdx.y * 256;
#pragma unroll
    for (int it = 0; it < 8; ++it) {
        int wl = it * 32 + (t >> 3), pl = (t & 7) * 8;
        *(half8*)&T[wl][pl] =
            *(const half8*)(p4 + (size_t)(w0 + wl) * 4096 + p0 + pl);
    }
    __syncthreads();
    float* ob = out + w0 + t;
#pragma unroll 4
    for (int p = 0; p < 64; ++p) {
        int cell = lut[p0 + p];                 // block-uniform -> scalar load
        ob[(size_t)cell * 4096] = (float)T[t][p];
    }
}

extern "C" void kernel_launch(void* const* d_in, const int* in_sizes, int n_in,
                              void* d_out, int out_size, void* d_ws, size_t ws_size,
                              hipStream_t stream) {
    const float* x     = (const float*)d_in[0];
    const float* wf    = (const float*)d_in[1];
    const float* uf    = (const float*)d_in[2];
    const float* biasf = (const float*)d_in[3];
    const float* wi    = (const float*)d_in[4];
    const float* ui    = (const float*)d_in[5];
    const float* biasi = (const float*)d_in[6];
    const float* wo    = (const float*)d_in[7];
    const float* uo    = (const float*)d_in[8];
    const float* biaso = (const float*)d_in[9];
    const float* wc    = (const float*)d_in[10];
    const float* uc    = (const float*)d_in[11];
    const float* biasc = (const float*)d_in[12];
    float* out = (float*)d_out;

    char*     gx  = (char*)d_ws;
    int*      lut = (int*)(gx + GX_BYTES);
    _Float16* wt  = (_Float16*)((char*)lut + 16384);

    lut_kernel<<<16, 256, 0, stream>>>(lut);
    prep_w<<<5, 256, 0, stream>>>(wf, wi, wo, wc, wt);
    gemm_kernel<<<dim3(32, 32), 256, 0, stream>>>(
        x, wt, biasf, biasi, biaso, biasc, lut, gx);
    recur_kernel<<<1024, 256, 0, stream>>>(gx, uf, ui, uo, uc);
    transpose_kernel<<<dim3(64, 16), 256, 0, stream>>>(gx, lut, out);
}